// Round 5
// baseline (125.645 us; speedup 1.0000x reference)
//
#include <hip/hip_runtime.h>
#include <hip/hip_bf16.h>

#define BATCH 8192
#define DIM 64
#define TINV 5.0f              // 1 / TEMPERATURE
#define SCALE5 7.21347520444f  // 5 * log2(e): A pre-scale so MFMA acc = log2(exp(sim/T))
#define EM4 0.01831563889f     // e^-4
#define MARGIN 0.8f
#define LGAMMA 0.5f
#define LREG 1e-4f

typedef __attribute__((ext_vector_type(8))) short short8;
typedef __attribute__((ext_vector_type(4))) float float4v;

__device__ __forceinline__ unsigned short f2bf(float f) {
    unsigned int u = __builtin_bit_cast(unsigned int, f);
    unsigned int r = (u + 0x7fffu + ((u >> 16) & 1u)) >> 16;  // round-nearest-even
    return (unsigned short)r;
}

// Phase 1: 4 rows per wave (float4/lane, 16-lane groups). Gathers ue/pe/ne,
// writes e1*SCALE5 and g = e1+e2 (bf16), pos_score[r]; block-reduces bpr/reg
// into per-block partials (no atomics). Also zeroes total[] + counters + scal.
// grid: 512 blocks x 256 thr = 2048 waves = 8192 rows.
__global__ __launch_bounds__(256) void phase1(
    const float* __restrict__ utab,
    const float* __restrict__ itab,
    const int* __restrict__ user, const int* __restrict__ posi,
    const int* __restrict__ negi,
    unsigned short* __restrict__ e1_out, unsigned short* __restrict__ g_out,
    float* __restrict__ pos_score, float* __restrict__ total,
    float* __restrict__ bpr_part, float* __restrict__ reg_part,
    unsigned int* __restrict__ misc /* cnt[128], done[1], scal[3] */)
{
    const int tid = blockIdx.x * 256 + threadIdx.x;
    if (tid < BATCH) total[tid] = 0.0f;             // stream order: done before phase2
    else if (tid < BATCH + 132) misc[tid - BATCH] = 0u;

    const int lane = threadIdx.x & 63;
    const int wv   = tid >> 6;
    const int l16  = lane & 15;
    const int r    = wv * 4 + (lane >> 4);          // this lane's row

    const int ui = user[r], pi = posi[r], ni = negi[r];
    const float4 u = *(const float4*)&utab[(size_t)ui * DIM + l16 * 4];
    const float4 p = *(const float4*)&itab[(size_t)pi * DIM + l16 * 4];
    const float4 n = *(const float4*)&itab[(size_t)ni * DIM + l16 * 4];

    float up = u.x*p.x + u.y*p.y + u.z*p.z + u.w*p.w;
    float un = u.x*n.x + u.y*n.y + u.z*n.z + u.w*n.w;
    float uu = u.x*u.x + u.y*u.y + u.z*u.z + u.w*u.w;
    float pp = p.x*p.x + p.y*p.y + p.z*p.z + p.w*p.w;
    float nn = n.x*n.x + n.y*n.y + n.z*n.z + n.w*n.w;
    #pragma unroll
    for (int off = 1; off < 16; off <<= 1) {        // reduce within 16-lane group
        up += __shfl_xor(up, off);
        un += __shfl_xor(un, off);
        uu += __shfl_xor(uu, off);
        pp += __shfl_xor(pp, off);
        nn += __shfl_xor(nn, off);
    }
    const float ia = 1.0f / fmaxf(sqrtf(uu), 1e-12f);   // e1 = u * ia
    const float ib = 1.0f / fmaxf(sqrtf(pp), 1e-12f);   // e2 = p * ib
    const float sa = SCALE5 * ia;

    union { unsigned short h[4]; uint2 v; } pe1, pg;
    pe1.h[0] = f2bf(u.x * sa); pe1.h[1] = f2bf(u.y * sa);
    pe1.h[2] = f2bf(u.z * sa); pe1.h[3] = f2bf(u.w * sa);
    pg.h[0]  = f2bf(u.x * ia + p.x * ib); pg.h[1] = f2bf(u.y * ia + p.y * ib);
    pg.h[2]  = f2bf(u.z * ia + p.z * ib); pg.h[3] = f2bf(u.w * ia + p.w * ib);
    *(uint2*)&e1_out[r * DIM + l16 * 4] = pe1.v;
    *(uint2*)&g_out[r * DIM + l16 * 4]  = pg.v;

    if (l16 == 0) {
        const float sim = up * (ia * ib);
        pos_score[r] = __expf(sim * TINV) + __expf(fmaxf(sim - MARGIN, 0.0f) * TINV);
    }
    // bpr/reg: every lane has its row's sums (broadcast by the xor-reduce)
    const float x  = up - un;                        // pos - neg (raw embeddings)
    float rb = fmaxf(-x, 0.0f) + __logf(1.0f + __expf(-fabsf(x)));
    float rr = uu + pp + nn;
    // sum the wave's 4 distinct rows (xor over subgroup bits only)
    rb += __shfl_xor(rb, 16); rb += __shfl_xor(rb, 32);
    rr += __shfl_xor(rr, 16); rr += __shfl_xor(rr, 32);
    // now every lane holds the wave's 4-row sum; cross-wave via LDS
    __shared__ float sb4[4], sr4[4];
    const int w = threadIdx.x >> 6;
    if (lane == 0) { sb4[w] = rb; sr4[w] = rr; }
    __syncthreads();
    if (threadIdx.x == 0) {
        bpr_part[blockIdx.x] = sb4[0] + sb4[1] + sb4[2] + sb4[3];
        reg_part[blockIdx.x] = sr4[0] + sr4[1] + sr4[2] + sr4[3];
    }
}

// Phase 2: total[i] = sum_j f(e1_i . g_j) via bf16 MFMA, fused epilogue:
// f = 2^t + max(2^t * e^-4, 1) with t = acc (A pre-scaled by 5*log2e).
// grid (128 stripes, 8 j-slices) x 256 thr. Per-stripe last-arriver computes
// the stripe's na partial; 128th stripe-finalizer writes out[0..2].
__global__ __launch_bounds__(256) void phase2(
    const unsigned short* __restrict__ e1,
    const unsigned short* __restrict__ g,
    float* __restrict__ total, const float* __restrict__ pos_score,
    const float* __restrict__ bpr_part, const float* __restrict__ reg_part,
    unsigned int* __restrict__ misc, float* __restrict__ out)
{
    unsigned int* cnt  = misc;          // [128]
    unsigned int* done = misc + 128;    // [1]
    float* scal = (float*)(misc + 129); // [3]: bpr, reg, na

    const int w = threadIdx.x >> 6;
    const int lane = threadIdx.x & 63;
    const int stripe = blockIdx.x;
    const int r0 = stripe * 64;
    const int jslice = blockIdx.y;          // 0..7, each covers 1024 cols
    const int rowsel = lane & 15;
    const int kbase = (lane >> 4) * 8;      // A/B frag: [m=lane&15][k=quad*8+j]

    short8 a[4][2];
    #pragma unroll
    for (int rt = 0; rt < 4; rt++)
        #pragma unroll
        for (int ks = 0; ks < 2; ks++)
            a[rt][ks] = *(const short8*)&e1[(r0 + rt * 16 + rowsel) * DIM + ks * 32 + kbase];

    float rowacc[4][4];
    #pragma unroll
    for (int rt = 0; rt < 4; rt++)
        #pragma unroll
        for (int q = 0; q < 4; q++) rowacc[rt][q] = 0.0f;

    for (int it = 0; it < 4; it++) {
        const int j0 = jslice * 1024 + it * 256 + w * 64;
        short8 b[4][2];
        #pragma unroll
        for (int ct = 0; ct < 4; ct++)
            #pragma unroll
            for (int ks = 0; ks < 2; ks++)
                b[ct][ks] = *(const short8*)&g[(j0 + ct * 16 + rowsel) * DIM + ks * 32 + kbase];

        #pragma unroll
        for (int rt = 0; rt < 4; rt++) {
            #pragma unroll
            for (int ct = 0; ct < 4; ct++) {
                float4v acc = {0.0f, 0.0f, 0.0f, 0.0f};
                acc = __builtin_amdgcn_mfma_f32_16x16x32_bf16(a[rt][0], b[ct][0], acc, 0, 0, 0);
                acc = __builtin_amdgcn_mfma_f32_16x16x32_bf16(a[rt][1], b[ct][1], acc, 0, 0, 0);
                #pragma unroll
                for (int q = 0; q < 4; q++) {
                    const float e = exp2f(acc[q]);
                    rowacc[rt][q] += e + fmaxf(e * EM4, 1.0f);
                }
            }
        }
    }

    // reduce across the 16 column-lanes (same lane>>4 group holds same rows)
    #pragma unroll
    for (int off = 1; off < 16; off <<= 1)
        #pragma unroll
        for (int rt = 0; rt < 4; rt++)
            #pragma unroll
            for (int q = 0; q < 4; q++)
                rowacc[rt][q] += __shfl_xor(rowacc[rt][q], off);

    if ((lane & 15) == 0) {
        const int rquad = lane >> 4;  // C/D layout: row = quad*4 + q
        #pragma unroll
        for (int rt = 0; rt < 4; rt++)
            #pragma unroll
            for (int q = 0; q < 4; q++)
                atomicAdd(&total[r0 + rt * 16 + rquad * 4 + q], rowacc[rt][q]);
    }

    // -------- per-stripe last-arriver: na partial for rows r0..r0+63 --------
    __syncthreads();                      // drains this block's vmem (waitcnt before barrier)
    __shared__ unsigned int lastf;
    if (threadIdx.x == 0) {
        __threadfence();                  // release our total[] adds
        lastf = (atomicAdd(&cnt[stripe], 1u) == 7u) ? 1u : 0u;
    }
    __syncthreads();
    if (lastf && threadIdx.x < 64) {
        __threadfence();                  // acquire the other 7 blocks' adds
        const int r = r0 + lane;
        const float tot = atomicAdd(&total[r], 0.0f);     // coherent read
        float v = -__logf(pos_score[r] / tot + 1e-5f);
        #pragma unroll
        for (int off = 1; off < 64; off <<= 1) v += __shfl_xor(v, off);
        if (lane == 0) {
            // this stripe also folds its slice of the phase1 partials (4 each)
            float sb = 0.0f, sr = 0.0f;
            #pragma unroll
            for (int k = 0; k < 4; k++) {
                sb += bpr_part[stripe * 4 + k];
                sr += reg_part[stripe * 4 + k];
            }
            atomicAdd(&scal[0], sb);
            atomicAdd(&scal[1], sr);
            atomicAdd(&scal[2], v);
            __threadfence();
            if (atomicAdd(done, 1u) == 127u) {            // very last stripe
                __threadfence();
                const float tb = atomicAdd(&scal[0], 0.0f);
                const float tr = atomicAdd(&scal[1], 0.0f);
                const float tn = atomicAdd(&scal[2], 0.0f);
                out[0] = tb / (float)BATCH;               // bpr
                out[1] = LREG * 0.5f * tr / (float)BATCH; // reg
                out[2] = LGAMMA * tn / (float)BATCH;      // na
            }
        }
    }
}

extern "C" void kernel_launch(void* const* d_in, const int* in_sizes, int n_in,
                              void* d_out, int out_size, void* d_ws, size_t ws_size,
                              hipStream_t stream) {
    const float* utab = (const float*)d_in[0];  // float32 [100000,64]
    const float* itab = (const float*)d_in[1];  // float32 [50000,64]
    const int* user = (const int*)d_in[2];
    const int* posi = (const int*)d_in[3];
    const int* negi = (const int*)d_in[4];

    char* ws = (char*)d_ws;
    unsigned short* e1 = (unsigned short*)ws;                              // 1 MiB
    unsigned short* g  = (unsigned short*)(ws + (size_t)BATCH * DIM * 2);  // 1 MiB
    float* pos_score   = (float*)(ws + 2 * (size_t)BATCH * DIM * 2);       // 32 KiB
    float* total       = pos_score + BATCH;                                // 32 KiB
    float* bpr_part    = total + BATCH;                                    // 2 KiB
    float* reg_part    = bpr_part + 512;                                   // 2 KiB
    unsigned int* misc = (unsigned int*)(reg_part + 512);                  // cnt[128]+done+scal[3]

    phase1<<<512, 256, 0, stream>>>(utab, itab, user, posi, negi,
                                    e1, g, pos_score, total,
                                    bpr_part, reg_part, misc);
    phase2<<<dim3(128, 8), 256, 0, stream>>>(e1, g, total, pos_score,
                                             bpr_part, reg_part, misc,
                                             (float*)d_out);
}

// Round 6
// 124.243 us; speedup vs baseline: 1.0113x; 1.0113x over previous
//
#include <hip/hip_runtime.h>
#include <hip/hip_bf16.h>

#define BATCH 8192
#define DIM 64
#define TINV 5.0f              // 1 / TEMPERATURE
#define SCALE5 7.21347520444f  // 5 * log2(e): A pre-scale so MFMA acc = log2(exp(sim/T))
#define CGT 1.01831563889f     // 1 + e^-4
#define MARGIN 0.8f
#define LGAMMA 0.5f
#define LREG 1e-4f

typedef __attribute__((ext_vector_type(8))) short short8;
typedef __attribute__((ext_vector_type(4))) float float4v;

__device__ __forceinline__ unsigned short f2bf(float f) {
    unsigned int u = __builtin_bit_cast(unsigned int, f);
    unsigned int r = (u + 0x7fffu + ((u >> 16) & 1u)) >> 16;  // round-nearest-even
    return (unsigned short)r;
}

// Phase 1: 2 rows per wave (float2/lane, 32-lane groups). Gathers ue/pe/ne,
// writes e1*SCALE5 and g = e1+e2 (bf16), pos_score / -logsigmoid / sumsq per
// row. Also zeroes total[] for phase2's atomics (stream order guarantees).
// grid: 1024 blocks x 256 thr = 4096 waves = 8192 rows. No atomics.
__global__ __launch_bounds__(256) void phase1(
    const float* __restrict__ utab,
    const float* __restrict__ itab,
    const int* __restrict__ user, const int* __restrict__ posi,
    const int* __restrict__ negi,
    unsigned short* __restrict__ e1_out, unsigned short* __restrict__ g_out,
    float* __restrict__ pos_score, float* __restrict__ row_bpr,
    float* __restrict__ row_reg, float* __restrict__ total)
{
    const int tid = blockIdx.x * 256 + threadIdx.x;
    if (tid < BATCH) total[tid] = 0.0f;   // done before phase2 launches

    const int lane = threadIdx.x & 63;
    const int wv   = tid >> 6;            // 0..4095
    const int l32  = lane & 31;
    const int r    = wv * 2 + (lane >> 5);

    const int ui = user[r], pi = posi[r], ni = negi[r];
    const float2 u = *(const float2*)&utab[(size_t)ui * DIM + l32 * 2];
    const float2 p = *(const float2*)&itab[(size_t)pi * DIM + l32 * 2];
    const float2 n = *(const float2*)&itab[(size_t)ni * DIM + l32 * 2];

    float up = u.x*p.x + u.y*p.y;
    float un = u.x*n.x + u.y*n.y;
    float uu = u.x*u.x + u.y*u.y;
    float pp = p.x*p.x + p.y*p.y;
    float nn = n.x*n.x + n.y*n.y;
    #pragma unroll
    for (int off = 1; off < 32; off <<= 1) {   // reduce within 32-lane group
        up += __shfl_xor(up, off);
        un += __shfl_xor(un, off);
        uu += __shfl_xor(uu, off);
        pp += __shfl_xor(pp, off);
        nn += __shfl_xor(nn, off);
    }
    const float ia = 1.0f / fmaxf(sqrtf(uu), 1e-12f);   // e1 = u * ia
    const float ib = 1.0f / fmaxf(sqrtf(pp), 1e-12f);   // e2 = p * ib
    const float sa = SCALE5 * ia;

    union { unsigned short h[2]; unsigned int v; } pe1, pg;
    pe1.h[0] = f2bf(u.x * sa); pe1.h[1] = f2bf(u.y * sa);
    pg.h[0]  = f2bf(u.x * ia + p.x * ib); pg.h[1] = f2bf(u.y * ia + p.y * ib);
    *(unsigned int*)&e1_out[r * DIM + l32 * 2] = pe1.v;
    *(unsigned int*)&g_out[r * DIM + l32 * 2]  = pg.v;

    if (l32 == 0) {
        const float sim = up * (ia * ib);
        pos_score[r] = __expf(sim * TINV) + __expf(fmaxf(sim - MARGIN, 0.0f) * TINV);
        const float x = up - un;   // pos - neg (raw embeddings)
        row_bpr[r] = fmaxf(-x, 0.0f) + __logf(1.0f + __expf(-fabsf(x)));
        row_reg[r] = uu + pp + nn;
    }
}

// Phase 2: total[i] = sum_j f(e1_i . g_j) via bf16 MFMA, fused epilogue.
// A pre-scaled by 5*log2e so t = acc, e = 2^t, and
// f = e + max(e*e^-4, 1) = max(e*(1+e^-4), e+1)   (same selector, 1 op less).
// Single-wave blocks for max occupancy: grid (256 stripes, 32 j-slices),
// each wave: 32-row stripe x 256 cols (4 j-tiles of 64).
__global__ __launch_bounds__(64, 6) void phase2(
    const unsigned short* __restrict__ e1,
    const unsigned short* __restrict__ g,
    float* __restrict__ total)
{
    const int lane = threadIdx.x;
    const int r0 = blockIdx.x * 32;
    const int jbase = blockIdx.y * 256;
    const int rowsel = lane & 15;
    const int kbase = (lane >> 4) * 8;      // A/B frag: [m=lane&15][k=quad*8+j]

    short8 a[2][2];
    #pragma unroll
    for (int rt = 0; rt < 2; rt++)
        #pragma unroll
        for (int ks = 0; ks < 2; ks++)
            a[rt][ks] = *(const short8*)&e1[(r0 + rt * 16 + rowsel) * DIM + ks * 32 + kbase];

    float rowacc[2][4];
    #pragma unroll
    for (int rt = 0; rt < 2; rt++)
        #pragma unroll
        for (int q = 0; q < 4; q++) rowacc[rt][q] = 0.0f;

    for (int it = 0; it < 4; it++) {
        const int j0 = jbase + it * 64;
        short8 b[4][2];
        #pragma unroll
        for (int ct = 0; ct < 4; ct++)
            #pragma unroll
            for (int ks = 0; ks < 2; ks++)
                b[ct][ks] = *(const short8*)&g[(j0 + ct * 16 + rowsel) * DIM + ks * 32 + kbase];

        #pragma unroll
        for (int rt = 0; rt < 2; rt++) {
            #pragma unroll
            for (int ct = 0; ct < 4; ct++) {
                float4v acc = {0.0f, 0.0f, 0.0f, 0.0f};
                acc = __builtin_amdgcn_mfma_f32_16x16x32_bf16(a[rt][0], b[ct][0], acc, 0, 0, 0);
                acc = __builtin_amdgcn_mfma_f32_16x16x32_bf16(a[rt][1], b[ct][1], acc, 0, 0, 0);
                #pragma unroll
                for (int q = 0; q < 4; q++) {
                    const float e = exp2f(acc[q]);
                    rowacc[rt][q] += fmaxf(e * CGT, e + 1.0f);
                }
            }
        }
    }

    // reduce across the 16 column-lanes (same lane>>4 group holds same rows)
    #pragma unroll
    for (int off = 1; off < 16; off <<= 1)
        #pragma unroll
        for (int rt = 0; rt < 2; rt++)
            #pragma unroll
            for (int q = 0; q < 4; q++)
                rowacc[rt][q] += __shfl_xor(rowacc[rt][q], off);

    if ((lane & 15) == 0) {
        const int rquad = lane >> 4;  // C/D layout: row = quad*4 + q
        #pragma unroll
        for (int rt = 0; rt < 2; rt++)
            #pragma unroll
            for (int q = 0; q < 4; q++)
                atomicAdd(&total[r0 + rt * 16 + rquad * 4 + q], rowacc[rt][q]);
    }
}

// Phase 3: final reductions -> THREE FLOAT32 outputs (bpr, reg, na).
// 1 block x 1024 threads, shuffle-reduce then LDS across 16 waves.
__global__ __launch_bounds__(1024) void phase3(
    const float* __restrict__ pos_score, const float* __restrict__ total,
    const float* __restrict__ row_bpr, const float* __restrict__ row_reg,
    float* __restrict__ out)
{
    __shared__ float rb[16], rr[16], rn[16];
    float sb = 0.0f, sr = 0.0f, sn = 0.0f;
    for (int i = threadIdx.x; i < BATCH; i += 1024) {
        sb += row_bpr[i];
        sr += row_reg[i];
        sn += -__logf(pos_score[i] / total[i] + 1e-5f);
    }
    #pragma unroll
    for (int off = 32; off; off >>= 1) {
        sb += __shfl_xor(sb, off);
        sr += __shfl_xor(sr, off);
        sn += __shfl_xor(sn, off);
    }
    const int wid = threadIdx.x >> 6;
    if ((threadIdx.x & 63) == 0) { rb[wid] = sb; rr[wid] = sr; rn[wid] = sn; }
    __syncthreads();
    if (threadIdx.x == 0) {
        float tb = 0.0f, tr = 0.0f, tn = 0.0f;
        #pragma unroll
        for (int i = 0; i < 16; i++) { tb += rb[i]; tr += rr[i]; tn += rn[i]; }
        out[0] = tb / (float)BATCH;                    // bpr
        out[1] = LREG * 0.5f * tr / (float)BATCH;      // reg
        out[2] = LGAMMA * (tn / (float)BATCH);         // na
    }
}

extern "C" void kernel_launch(void* const* d_in, const int* in_sizes, int n_in,
                              void* d_out, int out_size, void* d_ws, size_t ws_size,
                              hipStream_t stream) {
    const float* utab = (const float*)d_in[0];  // float32 [100000,64]
    const float* itab = (const float*)d_in[1];  // float32 [50000,64]
    const int* user = (const int*)d_in[2];
    const int* posi = (const int*)d_in[3];
    const int* negi = (const int*)d_in[4];

    char* ws = (char*)d_ws;
    unsigned short* e1 = (unsigned short*)ws;                              // 1 MiB
    unsigned short* g  = (unsigned short*)(ws + (size_t)BATCH * DIM * 2);  // 1 MiB
    float* pos_score   = (float*)(ws + 2 * (size_t)BATCH * DIM * 2);       // 32 KiB
    float* total       = pos_score + BATCH;                                // 32 KiB
    float* row_bpr     = total + BATCH;                                    // 32 KiB
    float* row_reg     = row_bpr + BATCH;                                  // 32 KiB

    phase1<<<1024, 256, 0, stream>>>(utab, itab, user, posi, negi,
                                     e1, g, pos_score, row_bpr, row_reg, total);
    phase2<<<dim3(256, 32), 64, 0, stream>>>(e1, g, total);
    phase3<<<1, 1024, 0, stream>>>(pos_score, total, row_bpr, row_reg,
                                   (float*)d_out);
}